// Round 8
// baseline (421.815 us; speedup 1.0000x reference)
//
#include <hip/hip_runtime.h>
#include <hip/hip_bf16.h>

typedef __attribute__((ext_vector_type(8))) short bf16x8;
typedef __attribute__((ext_vector_type(4))) float f32x4;
typedef __attribute__((ext_vector_type(8))) unsigned short u16x8;

__device__ __forceinline__ unsigned short bf16_rne(float f) {
  union { float f; unsigned u; } c; c.f = f;
  unsigned u = c.u;
  return (unsigned short)((u + 0x7FFFu + ((u >> 16) & 1u)) >> 16);
}

// one v_cvt_pk_bf16_f32: low16 = bf16(lo), high16 = bf16(hi), RNE
__device__ __forceinline__ unsigned cvt_pk_bf16(float lo, float hi) {
  unsigned r;
  asm("v_cvt_pk_bf16_f32 %0, %1, %2" : "=v"(r) : "v"(lo), "v"(hi));
  return r;
}

__device__ __forceinline__ bf16x8 pack4(unsigned a, unsigned b, unsigned c, unsigned d) {
  union { unsigned u[4]; bf16x8 v; } t;
  t.u[0] = a; t.u[1] = b; t.u[2] = c; t.u[3] = d;
  return t.v;
}

// ===================== prep0 =====================
__global__ void fecam_prep0(const float* __restrict__ w1, const float* __restrict__ w2,
                            const float* __restrict__ g, const float* __restrict__ bb,
                            unsigned short* __restrict__ Dbf, unsigned short* __restrict__ w2p,
                            float* __restrict__ Gv, float* __restrict__ Bv,
                            float* __restrict__ dsum) {
  int t = blockIdx.x * 256 + threadIdx.x;
  int lane = t & 63;
  int fr = t >> 6;
  int l16 = lane & 15, lh = lane >> 4;
  if (fr < 512) {            // Dbf: D[k][l] pack for prep1 B-operand
    int ks = fr >> 5, lf = fr & 31;
    int l = lf * 16 + l16;
    unsigned short o[8];
#pragma unroll
    for (int j = 0; j < 8; ++j) {
      int k = ks * 32 + lh * 8 + j;
      int tt = (k * (2 * l + 1)) & 2047;
      o[j] = bf16_rne(2.0f * cosf((float)tt * 3.0679615757712823e-3f));
    }
    *(u16x8*)(Dbf + (size_t)t * 8) = *(u16x8*)o;
  } else if (fr < 1536) {    // w2^T pack (K=1024: 32 ksteps, N=512: 32 nfrags)
    int fr2 = fr - 512;
    int nf = fr2 & 31;
    int ks = fr2 >> 5;
    int n = nf * 16 + l16;
    unsigned short o[8];
#pragma unroll
    for (int j = 0; j < 8; ++j) {
      int k = ks * 32 + lh * 8 + j;
      o[j] = bf16_rne(w2[(size_t)n * 1024 + k]);
    }
    *(u16x8*)(w2p + ((size_t)fr2 * 64 + lane) * 8) = *(u16x8*)o;
  } else if (fr < 1552) {    // Gv, Bv
    int n = (fr - 1536) * 64 + lane;
    float sg = 0.f, sb = 0.f;
    const float* wr = w1 + (size_t)n * 512;
#pragma unroll 4
    for (int k = 0; k < 512; k += 4) {
      float4 wv = *(const float4*)(wr + k);
      float4 gv = *(const float4*)(g + k);
      float4 bv = *(const float4*)(bb + k);
      sg += wv.x * gv.x + wv.y * gv.y + wv.z * gv.z + wv.w * gv.w;
      sb += wv.x * bv.x + wv.y * bv.y + wv.z * bv.z + wv.w * bv.w;
    }
    Gv[n] = sg; Bv[n] = sb;
  } else if (fr < 1560) {    // dsum
    int l = (fr - 1552) * 64 + lane;
    float s = 0.f;
    for (int k = 0; k < 512; ++k) {
      int tt = (k * (2 * l + 1)) & 2047;
      s += 2.0f * cosf((float)tt * 3.0679615757712823e-3f);
    }
    dsum[l] = s;
  }
}

// ===================== prep1: W1D = (w1 . g) @ D, packed =====================
__global__ void fecam_prep1(const float* __restrict__ w1, const float* __restrict__ g,
                            const unsigned short* __restrict__ Dbf,
                            unsigned short* __restrict__ W1Dp) {
  __shared__ float Cl[16][132];
  const int lane = threadIdx.x & 63;
  const int l16 = lane & 15, lh = lane >> 4;
  const int bi = blockIdx.x;
  const int n0 = (bi >> 2) * 16;
  const int l0 = (bi & 3) * 128;

  f32x4 acc[8];
#pragma unroll
  for (int jn = 0; jn < 8; ++jn) acc[jn] = (f32x4){0.f, 0.f, 0.f, 0.f};

  for (int ks = 0; ks < 16; ++ks) {
    int kbase = ks * 32 + lh * 8;
    const float* wr = w1 + (size_t)(n0 + l16) * 512 + kbase;
    float4 wa = *(const float4*)(wr);
    float4 wb = *(const float4*)(wr + 4);
    float4 ga = *(const float4*)(g + kbase);
    float4 gb = *(const float4*)(g + kbase + 4);
    bf16x8 af = pack4(cvt_pk_bf16(wa.x * ga.x, wa.y * ga.y),
                      cvt_pk_bf16(wa.z * ga.z, wa.w * ga.w),
                      cvt_pk_bf16(wb.x * gb.x, wb.y * gb.y),
                      cvt_pk_bf16(wb.z * gb.z, wb.w * gb.w));
#pragma unroll
    for (int jn = 0; jn < 8; ++jn) {
      bf16x8 bf = *(const bf16x8*)(Dbf + (((size_t)ks * 32 + (l0 >> 4) + jn) * 64 + lane) * 8);
      acc[jn] = __builtin_amdgcn_mfma_f32_16x16x32_bf16(af, bf, acc[jn], 0, 0, 0);
    }
  }
#pragma unroll
  for (int jn = 0; jn < 8; ++jn)
#pragma unroll
    for (int q = 0; q < 4; ++q) Cl[lh * 4 + q][jn * 16 + l16] = acc[jn][q];
  __syncthreads();
#pragma unroll
  for (int ks2 = 0; ks2 < 4; ++ks2) {
    float v[8];
#pragma unroll
    for (int j = 0; j < 8; ++j) v[j] = Cl[l16][ks2 * 32 + lh * 8 + j];
    unsigned short o[8];
#pragma unroll
    for (int j = 0; j < 8; j += 2) {
      unsigned pk = cvt_pk_bf16(v[j], v[j + 1]);
      o[j] = (unsigned short)pk;
      o[j + 1] = (unsigned short)(pk >> 16);
    }
    size_t idx = (((size_t)((l0 >> 5) + ks2) * 64 + (n0 >> 4)) * 64 + lane) * 8;
    *(u16x8*)(W1Dp + idx) = *(u16x8*)o;
  }
}

// ===================== kernel A: x -> h (global, swizzle-baked bf16) =====================
// BM=64 rows, 512 thr = 8 waves, LDS 66.3KB -> 2 blocks/CU. G2 in two N-halves,
// wave = 64 rows x 64 cols per half (acc2[4][4], only live acc). 2 barriers.
__global__ __launch_bounds__(512, 4) void fecam_g2(
    const float* __restrict__ x, const unsigned short* __restrict__ W1Dp,
    const float* __restrict__ Gv, const float* __restrict__ Bv,
    const float* __restrict__ dsum, unsigned short* __restrict__ hg) {
  extern __shared__ char smem[];          // [0,64K): x bf16 [64][512] swz
  float* ra = (float*)(smem + 65536);     // [64] sum x
  float* rb = ra + 64;                    // sum x^2
  float* rc = rb + 64;                    // sum x*dsum

  const int tid = threadIdx.x;
  const int lane = tid & 63;
  const int w = tid >> 6;                 // wave 0..7
  const int l16 = lane & 15, lh = lane >> 4;
  const int b = blockIdx.x >> 3;
  const int c0 = (blockIdx.x & 7) * 64;

  if (tid < 192) ra[tid] = 0.0f;
  __syncthreads();                        // bar0: zeroing before atomics

  // ---- stage x -> smem bf16 [64][512] swz; accumulate row stats ----
  {
    const int cc = lane;                  // row (c offset)
    const int kg = w;                     // 0..7
    const float* xb = x + ((size_t)b * 512) * 512 + c0 + cc;
    float s1 = 0.f, s2 = 0.f, sdp = 0.f;
#pragma unroll 8
    for (int kb = 0; kb < 32; ++kb) {
      int k = kb * 16 + kg * 2;
      float v0 = xb[(size_t)k * 512];
      float v1 = xb[(size_t)(k + 1) * 512];
      float2 dv = *(const float2*)(dsum + k);
      s1 += v0 + v1;
      s2 += v0 * v0 + v1 * v1;
      sdp += v0 * dv.x + v1 * dv.y;
      unsigned pk = cvt_pk_bf16(v0, v1);
      int byte = (cc * 1024 + k * 2) ^ ((cc & 7) << 4);
      *(unsigned*)(smem + byte) = pk;
    }
    atomicAdd(&ra[cc], s1);
    atomicAdd(&rb[cc], s2);
    atomicAdd(&rc[cc], sdp);
  }
  __syncthreads();                        // bar1: x + stats visible

  // ---- G2': two N-halves, h = relu(rstd*(x@W1D) - rstd*mu*Gn + Bn) ----
#pragma unroll 1
  for (int half = 0; half < 2; ++half) {
    float Gn_[4], Bn_[4];
#pragma unroll
    for (int jj = 0; jj < 4; ++jj) {
      int n = half * 512 + w * 64 + jj * 16 + l16;
      Gn_[jj] = Gv[n];
      Bn_[jj] = Bv[n];
    }
    f32x4 acc2[4][4];
#pragma unroll
    for (int i = 0; i < 4; ++i)
#pragma unroll
      for (int jj = 0; jj < 4; ++jj) acc2[i][jj] = (f32x4){0.f, 0.f, 0.f, 0.f};

#pragma unroll 2
    for (int ks = 0; ks < 16; ++ks) {
      bf16x8 af[4];
#pragma unroll
      for (int i = 0; i < 4; ++i) {
        int r = i * 16 + l16;
        int byte = (r * 1024 + ks * 64 + lh * 16) ^ ((r & 7) << 4);
        af[i] = *(const bf16x8*)(smem + byte);
      }
#pragma unroll
      for (int jj = 0; jj < 4; ++jj) {
        bf16x8 bf = *(const bf16x8*)(
            W1Dp + (((size_t)ks * 64 + half * 32 + w * 4 + jj) * 64 + lane) * 8);
#pragma unroll
        for (int i = 0; i < 4; ++i)
          acc2[i][jj] = __builtin_amdgcn_mfma_f32_16x16x32_bf16(af[i], bf, acc2[i][jj], 0, 0, 0);
      }
    }

    // epilogue: affine+relu, write h to global in swizzle-baked layout
#pragma unroll
    for (int i = 0; i < 4; ++i) {
      float mu_[4], rstd_[4];
#pragma unroll
      for (int q = 0; q < 4; ++q) {
        int r = i * 16 + lh * 4 + q;
        float s1 = ra[r], s2v = rb[r];
        float mu = rc[r] * (1.0f / 512.0f);
        float var = s1 * s1 * (1.0f / 256.0f) + 2.0f * s2v - mu * mu;
        mu_[q] = mu;
        rstd_[q] = rsqrtf(var + 1e-6f);
      }
#pragma unroll
      for (int jj = 0; jj < 4; ++jj) {
        int col = half * 512 + w * 64 + jj * 16 + l16;   // 0..1023
#pragma unroll
        for (int q = 0; q < 4; q += 2) {
          int r0 = i * 16 + lh * 4 + q;
          float c00 = fmaf(-rstd_[q] * mu_[q], Gn_[jj], Bn_[jj]);
          float c01 = fmaf(-rstd_[q + 1] * mu_[q + 1], Gn_[jj], Bn_[jj]);
          float v0 = fmaxf(fmaf(acc2[i][jj][q], rstd_[q], c00), 0.0f);
          float v1 = fmaxf(fmaf(acc2[i][jj][q + 1], rstd_[q + 1], c01), 0.0f);
          unsigned pk = cvt_pk_bf16(v0, v1);
          size_t g0 = (size_t)b * 512 + c0 + r0;          // global h row
          size_t i0 = g0 * 1024 + (col ^ ((r0 & 7) << 3));
          size_t i1 = (g0 + 1) * 1024 + (col ^ (((r0 + 1) & 7) << 3));
          hg[i0] = (unsigned short)pk;
          hg[i1] = (unsigned short)(pk >> 16);
        }
      }
    }
  }
}

// ===================== kernel B: h -> out =====================
// BM=32 rows, 512 thr = 8 waves, LDS 64.3KB -> 2 blocks/CU. Linear 64KB h-tile
// copy (swizzle baked by A). G3 wave = 32 rows x 64 cols (acc3[2][4]).
__global__ __launch_bounds__(512, 4) void fecam_g3(
    const float* __restrict__ x, const float* __restrict__ gamma,
    const float* __restrict__ beta, const unsigned short* __restrict__ hg,
    const unsigned short* __restrict__ w2p, float* __restrict__ out) {
  extern __shared__ char smem[];          // [0,64K): h tile [32][1024] bf16 swz
  float* rs2 = (float*)(smem + 65536);    // [32] LN2 sums
  float* rq2 = rs2 + 32;

  const int tid = threadIdx.x;
  const int lane = tid & 63;
  const int w = tid >> 6;                 // wave 0..7
  const int l16 = lane & 15, lh = lane >> 4;
  const int b = blockIdx.x >> 4;
  const int c0 = (blockIdx.x & 15) * 32;

  if (tid < 64) rs2[tid] = 0.0f;

  // ---- stage h tile: linear 64KB copy ----
  {
    const unsigned short* hsrc = hg + ((size_t)b * 512 + c0) * 1024;
#pragma unroll
    for (int it = 0; it < 8; ++it) {
      u16x8 v = *(const u16x8*)(hsrc + it * 4096 + tid * 8);
      *(u16x8*)(smem + it * 8192 + tid * 16) = v;
    }
  }

  float g_[4], b_[4];
#pragma unroll
  for (int jj = 0; jj < 4; ++jj) {
    g_[jj] = gamma[w * 64 + jj * 16 + l16];
    b_[jj] = beta[w * 64 + jj * 16 + l16];
  }
  __syncthreads();                        // bar0: h staged + stats zeroed

  // ---- G3: fw = h @ w2^T, K=1024, wave = 32 rows x 64 cols ----
  f32x4 acc3[2][4];
#pragma unroll
  for (int i = 0; i < 2; ++i)
#pragma unroll
    for (int jj = 0; jj < 4; ++jj) acc3[i][jj] = (f32x4){0.f, 0.f, 0.f, 0.f};

#pragma unroll 2
  for (int ks = 0; ks < 32; ++ks) {
    bf16x8 af[2];
#pragma unroll
    for (int i = 0; i < 2; ++i) {
      int r = i * 16 + l16;
      int byte = r * 2048 + ((ks * 64 + lh * 16) ^ ((r & 7) << 4));
      af[i] = *(const bf16x8*)(smem + byte);
    }
#pragma unroll
    for (int jj = 0; jj < 4; ++jj) {
      bf16x8 bf = *(const bf16x8*)(w2p + (((size_t)ks * 32 + w * 4 + jj) * 64 + lane) * 8);
#pragma unroll
      for (int i = 0; i < 2; ++i)
        acc3[i][jj] = __builtin_amdgcn_mfma_f32_16x16x32_bf16(af[i], bf, acc3[i][jj], 0, 0, 0);
    }
  }

  // ---- sigmoid ----
#pragma unroll
  for (int i = 0; i < 2; ++i)
#pragma unroll
    for (int jj = 0; jj < 4; ++jj)
#pragma unroll
      for (int q = 0; q < 4; ++q)
        acc3[i][jj][q] = 1.0f / (1.0f + __expf(-acc3[i][jj][q]));

  // ---- LN2 stats ----
#pragma unroll
  for (int i = 0; i < 2; ++i) {
#pragma unroll
    for (int q = 0; q < 4; ++q) {
      float s = acc3[i][0][q] + acc3[i][1][q] + acc3[i][2][q] + acc3[i][3][q];
      float ss = acc3[i][0][q] * acc3[i][0][q] + acc3[i][1][q] * acc3[i][1][q] +
                 acc3[i][2][q] * acc3[i][2][q] + acc3[i][3][q] * acc3[i][3][q];
#pragma unroll
      for (int m = 1; m <= 8; m <<= 1) {
        s += __shfl_xor(s, m);
        ss += __shfl_xor(ss, m);
      }
      if (l16 == 0) {
        atomicAdd(&rs2[i * 16 + lh * 4 + q], s);
        atomicAdd(&rq2[i * 16 + lh * 4 + q], ss);
      }
    }
  }
  __syncthreads();                        // bar1

  // ---- LN2 normalize, multiply by xp, store out[b][col][c0+r] ----
#pragma unroll
  for (int i = 0; i < 2; ++i) {
    float mu_[4], rstd_[4];
#pragma unroll
    for (int q = 0; q < 4; ++q) {
      int r = i * 16 + lh * 4 + q;
      float mu = rs2[r] * (1.0f / 512.0f);
      float var = rq2[r] * (1.0f / 512.0f) - mu * mu;
      mu_[q] = mu;
      rstd_[q] = rsqrtf(var + 1e-6f);
    }
#pragma unroll
    for (int jj = 0; jj < 4; ++jj) {
      int col = w * 64 + jj * 16 + l16;
      size_t base = ((size_t)b * 512 + col) * 512 + c0 + i * 16 + lh * 4;
      float4 xv = *(const float4*)(x + base);
      float4 ov;
#pragma unroll
      for (int q = 0; q < 4; ++q) {
        float fn = (acc3[i][jj][q] - mu_[q]) * rstd_[q] * g_[jj] + b_[jj];
        (&ov.x)[q] = (&xv.x)[q] * fn;
      }
      *(float4*)(out + base) = ov;
    }
  }
}

// ===================== fallback mono-kernel (R7, proven 315us) =====================
__global__ __launch_bounds__(1024, 4) void fecam_main(
    const float* __restrict__ x, const float* __restrict__ gamma, const float* __restrict__ beta,
    const unsigned short* __restrict__ W1Dp, const unsigned short* __restrict__ w2p,
    const float* __restrict__ Gv, const float* __restrict__ Bv,
    const float* __restrict__ dsum, float* __restrict__ out) {
  extern __shared__ char smem[];
  char* bufA = smem;
  char* bufB = smem + 65536;
  float* ra = (float*)(smem + 131072);
  float* rb = ra + 64;
  float* rc = rb + 64;
  float* rs2 = rc + 64;
  float* rq2 = rs2 + 64;

  const int tid = threadIdx.x;
  const int lane = tid & 63;
  const int w = tid >> 6;
  const int l16 = lane & 15, lh = lane >> 4;
  const int b = blockIdx.x >> 3;
  const int c0 = (blockIdx.x & 7) * 64;

  if (tid < 320) ra[tid] = 0.0f;
  __syncthreads();

  {
    const int cc = lane;
    const int kg = w;
    const float* xb = x + ((size_t)b * 512) * 512 + c0 + cc;
    float s1 = 0.f, s2 = 0.f, sdp = 0.f;
#pragma unroll
    for (int kb = 0; kb < 16; ++kb) {
      int k = kb * 32 + kg * 2;
      float v0 = xb[(size_t)k * 512];
      float v1 = xb[(size_t)(k + 1) * 512];
      float2 dv = *(const float2*)(dsum + k);
      s1 += v0 + v1;
      s2 += v0 * v0 + v1 * v1;
      sdp += v0 * dv.x + v1 * dv.y;
      unsigned pk = cvt_pk_bf16(v0, v1);
      int byte = (cc * 1024 + k * 2) ^ ((cc & 7) << 4);
      *(unsigned*)(bufA + byte) = pk;
    }
    atomicAdd(&ra[cc], s1);
    atomicAdd(&rb[cc], s2);
    atomicAdd(&rc[cc], sdp);
  }

  float g_[2], b_[2], Gn_[2][2], Bn_[2][2];
#pragma unroll
  for (int jj = 0; jj < 2; ++jj) {
    g_[jj] = gamma[w * 32 + jj * 16 + l16];
    b_[jj] = beta[w * 32 + jj * 16 + l16];
  }
#pragma unroll
  for (int hh = 0; hh < 2; ++hh)
#pragma unroll
    for (int jj = 0; jj < 2; ++jj) {
      int n = hh * 512 + w * 32 + jj * 16 + l16;
      Gn_[hh][jj] = Gv[n];
      Bn_[hh][jj] = Bv[n];
    }
  __syncthreads();

  f32x4 acc3[4][2];
#pragma unroll
  for (int i = 0; i < 4; ++i)
#pragma unroll
    for (int jj = 0; jj < 2; ++jj) acc3[i][jj] = (f32x4){0.f, 0.f, 0.f, 0.f};

#pragma unroll
  for (int half = 0; half < 2; ++half) {
    f32x4 acc2[4][2];
#pragma unroll
    for (int i = 0; i < 4; ++i)
#pragma unroll
      for (int jj = 0; jj < 2; ++jj) acc2[i][jj] = (f32x4){0.f, 0.f, 0.f, 0.f};

#pragma unroll 2
    for (int ks = 0; ks < 16; ++ks) {
      bf16x8 af[4];
#pragma unroll
      for (int i = 0; i < 4; ++i) {
        int r = i * 16 + l16;
        int byte = (r * 1024 + ks * 64 + lh * 16) ^ ((r & 7) << 4);
        af[i] = *(const bf16x8*)(bufA + byte);
      }
#pragma unroll
      for (int jj = 0; jj < 2; ++jj) {
        bf16x8 bf = *(const bf16x8*)(
            W1Dp + (((size_t)ks * 64 + half * 32 + w * 2 + jj) * 64 + lane) * 8);
#pragma unroll
        for (int i = 0; i < 4; ++i)
          acc2[i][jj] = __builtin_amdgcn_mfma_f32_16x16x32_bf16(af[i], bf, acc2[i][jj], 0, 0, 0);
      }
    }

    if (half == 1) __syncthreads();

    char* hbuf = half ? bufA : bufB;
#pragma unroll
    for (int i = 0; i < 4; ++i) {
      float mu_[4], rstd_[4];
#pragma unroll
      for (int q = 0; q < 4; ++q) {
        int r = i * 16 + lh * 4 + q;
        float s1 = ra[r], s2v = rb[r];
        float mu = rc[r] * (1.0f / 512.0f);
        float var = s1 * s1 * (1.0f / 256.0f) + 2.0f * s2v - mu * mu;
        mu_[q] = mu;
        rstd_[q] = rsqrtf(var + 1e-6f);
      }
#pragma unroll
      for (int jj = 0; jj < 2; ++jj) {
        int lc = w * 32 + jj * 16 + l16;
#pragma unroll
        for (int q = 0; q < 4; q += 2) {
          int r0 = i * 16 + lh * 4 + q;
          float c00 = fmaf(-rstd_[q] * mu_[q], Gn_[half][jj], Bn_[half][jj]);
          float c01 = fmaf(-rstd_[q + 1] * mu_[q + 1], Gn_[half][jj], Bn_[half][jj]);
          float v0 = fmaxf(fmaf(acc2[i][jj][q], rstd_[q], c00), 0.0f);
          float v1 = fmaxf(fmaf(acc2[i][jj][q + 1], rstd_[q + 1], c01), 0.0f);
          unsigned pk = cvt_pk_bf16(v0, v1);
          int byte0 = (r0 * 1024 + lc * 2) ^ ((r0 & 7) << 4);
          int byte1 = ((r0 + 1) * 1024 + lc * 2) ^ (((r0 + 1) & 7) << 4);
          *(unsigned short*)(hbuf + byte0) = (unsigned short)pk;
          *(unsigned short*)(hbuf + byte1) = (unsigned short)(pk >> 16);
        }
      }
    }
  }
  __syncthreads();

#pragma unroll 2
  for (int ks = 0; ks < 16; ++ks) {
    bf16x8 af[4];
#pragma unroll
    for (int i = 0; i < 4; ++i) {
      int r = i * 16 + l16;
      int byte = (r * 1024 + ks * 64 + lh * 16) ^ ((r & 7) << 4);
      af[i] = *(const bf16x8*)(bufB + byte);
    }
#pragma unroll
    for (int jj = 0; jj < 2; ++jj) {
      bf16x8 bf = *(const bf16x8*)(w2p + (((size_t)ks * 32 + w * 2 + jj) * 64 + lane) * 8);
#pragma unroll
      for (int i = 0; i < 4; ++i)
        acc3[i][jj] = __builtin_amdgcn_mfma_f32_16x16x32_bf16(af[i], bf, acc3[i][jj], 0, 0, 0);
    }
  }
#pragma unroll 2
  for (int ks = 0; ks < 16; ++ks) {
    bf16x8 af[4];
#pragma unroll
    for (int i = 0; i < 4; ++i) {
      int r = i * 16 + l16;
      int byte = (r * 1024 + ks * 64 + lh * 16) ^ ((r & 7) << 4);
      af[i] = *(const bf16x8*)(bufA + byte);
    }
#pragma unroll
    for (int jj = 0; jj < 2; ++jj) {
      bf16x8 bf = *(const bf16x8*)(
          w2p + (((size_t)(16 + ks) * 32 + w * 2 + jj) * 64 + lane) * 8);
#pragma unroll
      for (int i = 0; i < 4; ++i)
        acc3[i][jj] = __builtin_amdgcn_mfma_f32_16x16x32_bf16(af[i], bf, acc3[i][jj], 0, 0, 0);
    }
  }

#pragma unroll
  for (int i = 0; i < 4; ++i)
#pragma unroll
    for (int jj = 0; jj < 2; ++jj)
#pragma unroll
      for (int q = 0; q < 4; ++q)
        acc3[i][jj][q] = 1.0f / (1.0f + __expf(-acc3[i][jj][q]));

#pragma unroll
  for (int i = 0; i < 4; ++i) {
#pragma unroll
    for (int q = 0; q < 4; ++q) {
      float s = acc3[i][0][q] + acc3[i][1][q];
      float ss = acc3[i][0][q] * acc3[i][0][q] + acc3[i][1][q] * acc3[i][1][q];
#pragma unroll
      for (int m = 1; m <= 8; m <<= 1) {
        s += __shfl_xor(s, m);
        ss += __shfl_xor(ss, m);
      }
      if (l16 == 0) {
        atomicAdd(&rs2[i * 16 + lh * 4 + q], s);
        atomicAdd(&rq2[i * 16 + lh * 4 + q], ss);
      }
    }
  }
  __syncthreads();

#pragma unroll
  for (int i = 0; i < 4; ++i) {
    float mu_[4], rstd_[4];
#pragma unroll
    for (int q = 0; q < 4; ++q) {
      int r = i * 16 + lh * 4 + q;
      float mu = rs2[r] * (1.0f / 512.0f);
      float var = rq2[r] * (1.0f / 512.0f) - mu * mu;
      mu_[q] = mu;
      rstd_[q] = rsqrtf(var + 1e-6f);
    }
#pragma unroll
    for (int jj = 0; jj < 2; ++jj) {
      int col = w * 32 + jj * 16 + l16;
      size_t base = ((size_t)b * 512 + col) * 512 + c0 + i * 16 + lh * 4;
      float4 xv = *(const float4*)(x + base);
      float4 ov;
#pragma unroll
      for (int q = 0; q < 4; ++q) {
        float fn = (acc3[i][jj][q] - mu_[q]) * rstd_[q] * g_[jj] + b_[jj];
        (&ov.x)[q] = (&xv.x)[q] * fn;
      }
      *(float4*)(out + base) = ov;
    }
  }
}

extern "C" void kernel_launch(void* const* d_in, const int* in_sizes, int n_in,
                              void* d_out, int out_size, void* d_ws, size_t ws_size,
                              hipStream_t stream) {
  const float* x = (const float*)d_in[0];
  const float* gamma = (const float*)d_in[1];
  const float* beta = (const float*)d_in[2];
  const float* w1 = (const float*)d_in[3];
  const float* w2 = (const float*)d_in[4];

  unsigned short* w2p = (unsigned short*)d_ws;       // 524288 bf16
  unsigned short* W1Dp = w2p + 524288;               // 524288 bf16
  unsigned short* Dbf = W1Dp + 524288;               // 262144 bf16
  float* Gv = (float*)(Dbf + 262144);                // 1024 f32
  float* Bv = Gv + 1024;                             // 1024 f32
  float* dsum = Bv + 1024;                           // 512 f32
  unsigned short* hg = (unsigned short*)(dsum + 512); // 65536*1024 bf16 = 128MB

  const size_t need = 2631680ULL + 134217728ULL;     // weights + h buffer

  fecam_prep0<<<390, 256, 0, stream>>>(w1, w2, gamma, beta, Dbf, w2p, Gv, Bv, dsum);
  fecam_prep1<<<256, 64, 0, stream>>>(w1, gamma, Dbf, W1Dp);

  if (ws_size >= need) {
    fecam_g2<<<1024, 512, 66304, stream>>>(x, W1Dp, Gv, Bv, dsum, hg);
    fecam_g3<<<2048, 512, 65792, stream>>>(x, gamma, beta, hg, w2p, (float*)d_out);
  } else {
    fecam_main<<<1024, 1024, 132416, stream>>>(x, gamma, beta, W1Dp, w2p, Gv, Bv, dsum,
                                               (float*)d_out);
  }
}

// Round 9
// 379.341 us; speedup vs baseline: 1.1120x; 1.1120x over previous
//
#include <hip/hip_runtime.h>
#include <hip/hip_bf16.h>

typedef __attribute__((ext_vector_type(8))) short bf16x8;
typedef __attribute__((ext_vector_type(4))) float f32x4;
typedef __attribute__((ext_vector_type(8))) unsigned short u16x8;

__device__ __forceinline__ unsigned short bf16_rne(float f) {
  union { float f; unsigned u; } c; c.f = f;
  unsigned u = c.u;
  return (unsigned short)((u + 0x7FFFu + ((u >> 16) & 1u)) >> 16);
}

// one v_cvt_pk_bf16_f32: low16 = bf16(lo), high16 = bf16(hi), RNE
__device__ __forceinline__ unsigned cvt_pk_bf16(float lo, float hi) {
  unsigned r;
  asm("v_cvt_pk_bf16_f32 %0, %1, %2" : "=v"(r) : "v"(lo), "v"(hi));
  return r;
}

__device__ __forceinline__ bf16x8 pack4(unsigned a, unsigned b, unsigned c, unsigned d) {
  union { unsigned u[4]; bf16x8 v; } t;
  t.u[0] = a; t.u[1] = b; t.u[2] = c; t.u[3] = d;
  return t.v;
}

// ===================== prep0 =====================
__global__ void fecam_prep0(const float* __restrict__ w1, const float* __restrict__ w2,
                            const float* __restrict__ g, const float* __restrict__ bb,
                            unsigned short* __restrict__ Dbf, unsigned short* __restrict__ w2p,
                            float* __restrict__ Gv, float* __restrict__ Bv,
                            float* __restrict__ dsum) {
  int t = blockIdx.x * 256 + threadIdx.x;
  int lane = t & 63;
  int fr = t >> 6;
  int l16 = lane & 15, lh = lane >> 4;
  if (fr < 512) {            // Dbf: D[k][l] pack for prep1 B-operand
    int ks = fr >> 5, lf = fr & 31;
    int l = lf * 16 + l16;
    unsigned short o[8];
#pragma unroll
    for (int j = 0; j < 8; ++j) {
      int k = ks * 32 + lh * 8 + j;
      int tt = (k * (2 * l + 1)) & 2047;
      o[j] = bf16_rne(2.0f * cosf((float)tt * 3.0679615757712823e-3f));
    }
    *(u16x8*)(Dbf + (size_t)t * 8) = *(u16x8*)o;
  } else if (fr < 1536) {    // w2^T pack (K=1024: 32 ksteps, N=512: 32 nfrags)
    int fr2 = fr - 512;
    int nf = fr2 & 31;
    int ks = fr2 >> 5;
    int n = nf * 16 + l16;
    unsigned short o[8];
#pragma unroll
    for (int j = 0; j < 8; ++j) {
      int k = ks * 32 + lh * 8 + j;
      o[j] = bf16_rne(w2[(size_t)n * 1024 + k]);
    }
    *(u16x8*)(w2p + ((size_t)fr2 * 64 + lane) * 8) = *(u16x8*)o;
  } else if (fr < 1552) {    // Gv, Bv
    int n = (fr - 1536) * 64 + lane;
    float sg = 0.f, sb = 0.f;
    const float* wr = w1 + (size_t)n * 512;
#pragma unroll 4
    for (int k = 0; k < 512; k += 4) {
      float4 wv = *(const float4*)(wr + k);
      float4 gv = *(const float4*)(g + k);
      float4 bv = *(const float4*)(bb + k);
      sg += wv.x * gv.x + wv.y * gv.y + wv.z * gv.z + wv.w * gv.w;
      sb += wv.x * bv.x + wv.y * bv.y + wv.z * bv.z + wv.w * bv.w;
    }
    Gv[n] = sg; Bv[n] = sb;
  } else if (fr < 1560) {    // dsum
    int l = (fr - 1552) * 64 + lane;
    float s = 0.f;
    for (int k = 0; k < 512; ++k) {
      int tt = (k * (2 * l + 1)) & 2047;
      s += 2.0f * cosf((float)tt * 3.0679615757712823e-3f);
    }
    dsum[l] = s;
  }
}

// ===================== prep1: W1D = (w1 . g) @ D, packed =====================
// 64 blocks x 256 thr (4 waves); wave = one (n0, l0) tile of the 256.
__global__ void fecam_prep1(const float* __restrict__ w1, const float* __restrict__ g,
                            const unsigned short* __restrict__ Dbf,
                            unsigned short* __restrict__ W1Dp) {
  __shared__ float Cl[4][16][132];
  const int tid = threadIdx.x;
  const int lane = tid & 63;
  const int wv = tid >> 6;
  const int l16 = lane & 15, lh = lane >> 4;
  const int bi = blockIdx.x * 4 + wv;      // 0..255
  const int n0 = (bi >> 2) * 16;
  const int l0 = (bi & 3) * 128;

  f32x4 acc[8];
#pragma unroll
  for (int jn = 0; jn < 8; ++jn) acc[jn] = (f32x4){0.f, 0.f, 0.f, 0.f};

  for (int ks = 0; ks < 16; ++ks) {
    int kbase = ks * 32 + lh * 8;
    const float* wr = w1 + (size_t)(n0 + l16) * 512 + kbase;
    float4 wa = *(const float4*)(wr);
    float4 wb = *(const float4*)(wr + 4);
    float4 ga = *(const float4*)(g + kbase);
    float4 gb = *(const float4*)(g + kbase + 4);
    bf16x8 af = pack4(cvt_pk_bf16(wa.x * ga.x, wa.y * ga.y),
                      cvt_pk_bf16(wa.z * ga.z, wa.w * ga.w),
                      cvt_pk_bf16(wb.x * gb.x, wb.y * gb.y),
                      cvt_pk_bf16(wb.z * gb.z, wb.w * gb.w));
#pragma unroll
    for (int jn = 0; jn < 8; ++jn) {
      bf16x8 bf = *(const bf16x8*)(Dbf + (((size_t)ks * 32 + (l0 >> 4) + jn) * 64 + lane) * 8);
      acc[jn] = __builtin_amdgcn_mfma_f32_16x16x32_bf16(af, bf, acc[jn], 0, 0, 0);
    }
  }
#pragma unroll
  for (int jn = 0; jn < 8; ++jn)
#pragma unroll
    for (int q = 0; q < 4; ++q) Cl[wv][lh * 4 + q][jn * 16 + l16] = acc[jn][q];
  __syncthreads();
#pragma unroll
  for (int ks2 = 0; ks2 < 4; ++ks2) {
    float v[8];
#pragma unroll
    for (int j = 0; j < 8; ++j) v[j] = Cl[wv][l16][ks2 * 32 + lh * 8 + j];
    unsigned short o[8];
#pragma unroll
    for (int j = 0; j < 8; j += 2) {
      unsigned pk = cvt_pk_bf16(v[j], v[j + 1]);
      o[j] = (unsigned short)pk;
      o[j + 1] = (unsigned short)(pk >> 16);
    }
    size_t idx = (((size_t)((l0 >> 5) + ks2) * 64 + (n0 >> 4)) * 64 + lane) * 8;
    *(u16x8*)(W1Dp + idx) = *(u16x8*)o;
  }
}

// ===================== fused main (R7 structure + b128 staging + unroll 4) =====================
__global__ __launch_bounds__(1024, 4) void fecam_main(
    const float* __restrict__ x, const float* __restrict__ gamma, const float* __restrict__ beta,
    const unsigned short* __restrict__ W1Dp, const unsigned short* __restrict__ w2p,
    const float* __restrict__ Gv, const float* __restrict__ Bv,
    const float* __restrict__ dsum, float* __restrict__ out) {
  extern __shared__ char smem[];
  char* bufA = smem;                 // x bf16 [64][512] swz -> h half1
  char* bufB = smem + 65536;         // h half0 [64][512] swz
  float* ra = (float*)(smem + 131072);  // [64] sum x
  float* rb = ra + 64;                   // sum x^2
  float* rc = rb + 64;                   // sum x*dsum
  float* rs2 = rc + 64;                  // LN2 sums
  float* rq2 = rs2 + 64;                 // LN2 sumsq

  const int tid = threadIdx.x;
  const int lane = tid & 63;
  const int w = tid >> 6;            // wave 0..15
  const int l16 = lane & 15, lh = lane >> 4;
  const int b = blockIdx.x >> 3;
  const int c0 = (blockIdx.x & 7) * 64;

  if (tid < 320) ra[tid] = 0.0f;     // zero all 5 stat arrays
  __syncthreads();                   // bar0: zeroing visible before atomics

  // ---- stage x -> bufA bf16 [64][512] swz via ds_write_b128 (conflict-free) ----
  {
    const int cc = lane;             // row (c offset)
    const float* xb = x + ((size_t)b * 512) * 512 + c0 + cc;
    float s1 = 0.f, s2 = 0.f, sdp = 0.f;
#pragma unroll
    for (int gblk = 0; gblk < 4; ++gblk) {
      int k0 = w * 32 + gblk * 8;    // 8 consecutive k per write
      float4 d0 = *(const float4*)(dsum + k0);
      float4 d1 = *(const float4*)(dsum + k0 + 4);
      float v[8];
#pragma unroll
      for (int j = 0; j < 8; ++j) {
        v[j] = xb[(size_t)(k0 + j) * 512];
        s1 += v[j];
        s2 += v[j] * v[j];
      }
      sdp += v[0] * d0.x + v[1] * d0.y + v[2] * d0.z + v[3] * d0.w +
             v[4] * d1.x + v[5] * d1.y + v[6] * d1.z + v[7] * d1.w;
      unsigned short o[8];
#pragma unroll
      for (int j = 0; j < 8; j += 2) {
        unsigned pk = cvt_pk_bf16(v[j], v[j + 1]);
        o[j] = (unsigned short)pk;
        o[j + 1] = (unsigned short)(pk >> 16);
      }
      int byte = (cc * 1024 + k0 * 2) ^ ((cc & 7) << 4);
      *(u16x8*)(bufA + byte) = *(u16x8*)o;
    }
    atomicAdd(&ra[cc], s1);
    atomicAdd(&rb[cc], s2);
    atomicAdd(&rc[cc], sdp);
  }

  // per-wave constants (overlap staging latency)
  float g_[2], b_[2], Gn_[2][2], Bn_[2][2];
#pragma unroll
  for (int jj = 0; jj < 2; ++jj) {
    g_[jj] = gamma[w * 32 + jj * 16 + l16];
    b_[jj] = beta[w * 32 + jj * 16 + l16];
  }
#pragma unroll
  for (int hh = 0; hh < 2; ++hh)
#pragma unroll
    for (int jj = 0; jj < 2; ++jj) {
      int n = hh * 512 + w * 32 + jj * 16 + l16;
      Gn_[hh][jj] = Gv[n];
      Bn_[hh][jj] = Bv[n];
    }

  __syncthreads();                   // bar1: x + stats visible

  f32x4 acc3[4][2];
#pragma unroll
  for (int i = 0; i < 4; ++i)
#pragma unroll
    for (int jj = 0; jj < 2; ++jj) acc3[i][jj] = (f32x4){0.f, 0.f, 0.f, 0.f};

  // ======== G2' two halves ========
#pragma unroll
  for (int half = 0; half < 2; ++half) {
    f32x4 acc2[4][2];
#pragma unroll
    for (int i = 0; i < 4; ++i)
#pragma unroll
      for (int jj = 0; jj < 2; ++jj) acc2[i][jj] = (f32x4){0.f, 0.f, 0.f, 0.f};

#pragma unroll 4
    for (int ks = 0; ks < 16; ++ks) {
      bf16x8 af[4];
#pragma unroll
      for (int i = 0; i < 4; ++i) {
        int r = i * 16 + l16;
        int byte = (r * 1024 + ks * 64 + lh * 16) ^ ((r & 7) << 4);
        af[i] = *(const bf16x8*)(bufA + byte);
      }
#pragma unroll
      for (int jj = 0; jj < 2; ++jj) {
        bf16x8 bf = *(const bf16x8*)(
            W1Dp + (((size_t)ks * 64 + half * 32 + w * 2 + jj) * 64 + lane) * 8);
#pragma unroll
        for (int i = 0; i < 4; ++i)
          acc2[i][jj] = __builtin_amdgcn_mfma_f32_16x16x32_bf16(af[i], bf, acc2[i][jj], 0, 0, 0);
      }
    }

    if (half == 1) __syncthreads();  // bar2: all x reads done before overwrite

    char* hbuf = half ? bufA : bufB;
#pragma unroll
    for (int i = 0; i < 4; ++i) {
      float mu_[4], rstd_[4];
#pragma unroll
      for (int q = 0; q < 4; ++q) {
        int r = i * 16 + lh * 4 + q;
        float s1 = ra[r], s2v = rb[r];
        float mu = rc[r] * (1.0f / 512.0f);
        float var = s1 * s1 * (1.0f / 256.0f) + 2.0f * s2v - mu * mu;
        mu_[q] = mu;
        rstd_[q] = rsqrtf(var + 1e-6f);
      }
#pragma unroll
      for (int jj = 0; jj < 2; ++jj) {
        int lc = w * 32 + jj * 16 + l16;
#pragma unroll
        for (int q = 0; q < 4; q += 2) {
          int r0 = i * 16 + lh * 4 + q;
          float c00 = fmaf(-rstd_[q] * mu_[q], Gn_[half][jj], Bn_[half][jj]);
          float c01 = fmaf(-rstd_[q + 1] * mu_[q + 1], Gn_[half][jj], Bn_[half][jj]);
          float v0 = fmaxf(fmaf(acc2[i][jj][q], rstd_[q], c00), 0.0f);
          float v1 = fmaxf(fmaf(acc2[i][jj][q + 1], rstd_[q + 1], c01), 0.0f);
          unsigned pk = cvt_pk_bf16(v0, v1);
          int byte0 = (r0 * 1024 + lc * 2) ^ ((r0 & 7) << 4);
          int byte1 = ((r0 + 1) * 1024 + lc * 2) ^ (((r0 + 1) & 7) << 4);
          *(unsigned short*)(hbuf + byte0) = (unsigned short)pk;
          *(unsigned short*)(hbuf + byte1) = (unsigned short)(pk >> 16);
        }
      }
    }
  }
  __syncthreads();                   // bar3: h complete

  // ======== G3: fw = h @ w2^T, K=1024 (bufB then bufA) ========
#pragma unroll 4
  for (int ks = 0; ks < 16; ++ks) {
    bf16x8 af[4];
#pragma unroll
    for (int i = 0; i < 4; ++i) {
      int r = i * 16 + l16;
      int byte = (r * 1024 + ks * 64 + lh * 16) ^ ((r & 7) << 4);
      af[i] = *(const bf16x8*)(bufB + byte);
    }
#pragma unroll
    for (int jj = 0; jj < 2; ++jj) {
      bf16x8 bf = *(const bf16x8*)(w2p + (((size_t)ks * 32 + w * 2 + jj) * 64 + lane) * 8);
#pragma unroll
      for (int i = 0; i < 4; ++i)
        acc3[i][jj] = __builtin_amdgcn_mfma_f32_16x16x32_bf16(af[i], bf, acc3[i][jj], 0, 0, 0);
    }
  }
#pragma unroll 4
  for (int ks = 0; ks < 16; ++ks) {
    bf16x8 af[4];
#pragma unroll
    for (int i = 0; i < 4; ++i) {
      int r = i * 16 + l16;
      int byte = (r * 1024 + ks * 64 + lh * 16) ^ ((r & 7) << 4);
      af[i] = *(const bf16x8*)(bufA + byte);
    }
#pragma unroll
    for (int jj = 0; jj < 2; ++jj) {
      bf16x8 bf = *(const bf16x8*)(
          w2p + (((size_t)(16 + ks) * 32 + w * 2 + jj) * 64 + lane) * 8);
#pragma unroll
      for (int i = 0; i < 4; ++i)
        acc3[i][jj] = __builtin_amdgcn_mfma_f32_16x16x32_bf16(af[i], bf, acc3[i][jj], 0, 0, 0);
    }
  }

  // ---- sigmoid ----
#pragma unroll
  for (int i = 0; i < 4; ++i)
#pragma unroll
    for (int jj = 0; jj < 2; ++jj)
#pragma unroll
      for (int q = 0; q < 4; ++q)
        acc3[i][jj][q] = 1.0f / (1.0f + __expf(-acc3[i][jj][q]));

  // ---- LN2 stats ----
#pragma unroll
  for (int i = 0; i < 4; ++i) {
#pragma unroll
    for (int q = 0; q < 4; ++q) {
      float s = acc3[i][0][q] + acc3[i][1][q];
      float ss = acc3[i][0][q] * acc3[i][0][q] + acc3[i][1][q] * acc3[i][1][q];
#pragma unroll
      for (int m = 1; m <= 8; m <<= 1) {
        s += __shfl_xor(s, m);
        ss += __shfl_xor(ss, m);
      }
      if (l16 == 0) {
        atomicAdd(&rs2[i * 16 + lh * 4 + q], s);
        atomicAdd(&rq2[i * 16 + lh * 4 + q], ss);
      }
    }
  }
  __syncthreads();                   // bar4

  // ---- LN2 normalize, multiply by xp, store out[b][col][c0+r] ----
#pragma unroll
  for (int i = 0; i < 4; ++i) {
    float mu_[4], rstd_[4];
#pragma unroll
    for (int q = 0; q < 4; ++q) {
      int r = i * 16 + lh * 4 + q;
      float mu = rs2[r] * (1.0f / 512.0f);
      float var = rq2[r] * (1.0f / 512.0f) - mu * mu;
      mu_[q] = mu;
      rstd_[q] = rsqrtf(var + 1e-6f);
    }
#pragma unroll
    for (int jj = 0; jj < 2; ++jj) {
      int col = w * 32 + jj * 16 + l16;
      size_t base = ((size_t)b * 512 + col) * 512 + c0 + i * 16 + lh * 4;
      float4 xv = *(const float4*)(x + base);
      float4 ov;
#pragma unroll
      for (int q = 0; q < 4; ++q) {
        float fn = (acc3[i][jj][q] - mu_[q]) * rstd_[q] * g_[jj] + b_[jj];
        (&ov.x)[q] = (&xv.x)[q] * fn;
      }
      *(float4*)(out + base) = ov;
    }
  }
}

extern "C" void kernel_launch(void* const* d_in, const int* in_sizes, int n_in,
                              void* d_out, int out_size, void* d_ws, size_t ws_size,
                              hipStream_t stream) {
  const float* x = (const float*)d_in[0];
  const float* gamma = (const float*)d_in[1];
  const float* beta = (const float*)d_in[2];
  const float* w1 = (const float*)d_in[3];
  const float* w2 = (const float*)d_in[4];

  unsigned short* w2p = (unsigned short*)d_ws;       // 524288 bf16
  unsigned short* W1Dp = w2p + 524288;               // 524288 bf16
  unsigned short* Dbf = W1Dp + 524288;               // 262144 bf16
  float* Gv = (float*)(Dbf + 262144);                // 1024 f32
  float* Bv = Gv + 1024;                             // 1024 f32
  float* dsum = Bv + 1024;                           // 512 f32

  fecam_prep0<<<390, 256, 0, stream>>>(w1, w2, gamma, beta, Dbf, w2p, Gv, Bv, dsum);
  fecam_prep1<<<64, 256, 0, stream>>>(w1, gamma, Dbf, W1Dp);
  fecam_main<<<1024, 1024, 132416, stream>>>(x, gamma, beta, W1Dp, w2p, Gv, Bv, dsum,
                                             (float*)d_out);
}